// Round 6
// baseline (528.488 us; speedup 1.0000x reference)
//
#include <hip/hip_runtime.h>
#include <hip/hip_bf16.h>

// ESA_SMILES fused pipeline for MI355X (gfx950).
// Identity: cap = LN(x)@W1^T+b1 ; feat = cap@W2^T+b2 = LN(x)@(W2W1)^T+(W2b1+b2)
// out[b,d] = sum_n exp(feat[n,d])*cap[n,d] / sum_n exp(feat[n,d])
//
// R11 = R5 geometry exactly (64-row blocks, 2 blocks/CU, 16x16x32 MFMA,
// grid=maxent fresh blocks) + intra-entry M-split pipeline:
//  - mt{0,1} accumulators need only y rows 0..31 -> LN(rows 0-31), barrier,
//    GEMM part1 (mt 0,1) WHILE rows 32-63 x-loads are in flight (issued
//    pre-barrier, consumed post-part1), LN finish, barrier, part2 + grp1.
//    Hides the 2nd half of LN (HBM latency + VALU) under 128 real MFMAs.
//  - register peak in part1: acc 32 + prefetch 32 + frags/addr ~40 ~= 105
//    < 128 (R6's spill trap avoided: prefetch spans half a group, not the
//    whole GEMM). Barriers still 2/entry. grp0 B-frags re-read once
//    (+0.5MB/block, L2 ~18 TB/s << 34.5 ceiling).
//  - R10 post-mortem: 6-wave occupancy cap spilled the accumulators
//    (WRITE_SIZE 39MB, VGPR=40 < acc48). 4 waves/SIMD is the feasible max.

typedef short short8 __attribute__((ext_vector_type(8)));   // 8 x bf16
typedef short short4v __attribute__((ext_vector_type(4)));
typedef float f32x4 __attribute__((ext_vector_type(4)));

__device__ inline short f2bf(float f) {
    unsigned u = __float_as_uint(f);
    u += 0x7fffu + ((u >> 16) & 1u);     // round-to-nearest-even
    return (short)(u >> 16);
}

// packed offset for element (n, k) of a 512x512 weight matrix in the
// B-fragment order of mfma_f32_16x16x32_bf16 (R5-verified):
//   t = n>>4, k0 = k>>5, lane = ((k>>3)&3)*16 + (n&15), j = k&7
__device__ inline size_t packed_off(int n, int k) {
    const int t = n >> 4, l16n = n & 15;
    const int k0 = k >> 5, quad = (k >> 3) & 3, j = k & 7;
    return ((size_t)((t * 16 + k0) * 64 + quad * 16 + l16n)) * 8 + j;
}

// ---------------------------------------------------------------------------
// prep_all: ONE dispatch, role-split blocks (512 threads each):
//   blocks 0..63    : W12p = bf16(W2) @ bf16(W1) via MFMA -> packed layout
//   blocks 64..191  : W1 fp32 -> bf16, packed layout (W1p)
//   blocks 192..195 : b12 = W2@b1 + b2 (4 blocks x 128 rows, 4 thr/row)
//   block  196      : entries (binary search on sorted data_batch)
//   blocks 197..228 : zero num/den
// ---------------------------------------------------------------------------
#define PREP_GRID 229

__global__ __launch_bounds__(512)
void esa_prep_all(const float* __restrict__ W1, const float* __restrict__ W2,
                  const float* __restrict__ b1, const float* __restrict__ b2,
                  const int* __restrict__ db, int T, int B,
                  short* __restrict__ W1p, short* __restrict__ W12p,
                  float* __restrict__ b12, int4* __restrict__ entries, int maxent,
                  float* __restrict__ numden) {
    __shared__ int off[513];
    __shared__ int nch[512];
    __shared__ int scan[513];
    const int bid = blockIdx.x;
    const int tid = threadIdx.x;

    if (bid < 64) {
        // ---- W12 tile (64x64) via MFMA, converting fp32->bf16 on the fly
        const int ti = bid >> 3, tj = bid & 7;
        const int wave = tid >> 6;          // 0..7
        const int lane = tid & 63;
        const int quad = lane >> 4;
        const int l16 = lane & 15;
        const int mhalf = wave >> 2;        // rows half (m-tiles 0-1 or 2-3)
        const int kq = wave & 3;
        const int kcol = tj * 64 + kq * 16 + l16;

        f32x4 acc[2];
        acc[0] = (f32x4)0.0f; acc[1] = (f32x4)0.0f;
        for (int j0 = 0; j0 < 512; j0 += 32) {
            short8 bfr;
#pragma unroll
            for (int jj = 0; jj < 8; ++jj)
                bfr[jj] = f2bf(W1[(size_t)(j0 + quad * 8 + jj) * 512 + kcol]);
#pragma unroll
            for (int mt = 0; mt < 2; ++mt) {
                const float* ar = W2 + (size_t)(ti * 64 + (mhalf * 2 + mt) * 16 + l16) * 512 +
                                  j0 + quad * 8;
                const float4 a0 = *(const float4*)ar;
                const float4 a1 = *(const float4*)(ar + 4);
                short8 afr = {f2bf(a0.x), f2bf(a0.y), f2bf(a0.z), f2bf(a0.w),
                              f2bf(a1.x), f2bf(a1.y), f2bf(a1.z), f2bf(a1.w)};
                acc[mt] = __builtin_amdgcn_mfma_f32_16x16x32_bf16(afr, bfr,
                                                                  acc[mt], 0, 0, 0);
            }
        }
        // C/D layout: col(k) = lane&15, row(n) = quad*4 + r -> packed store
#pragma unroll
        for (int mt = 0; mt < 2; ++mt)
#pragma unroll
            for (int r = 0; r < 4; ++r) {
                const int n = ti * 64 + (mhalf * 2 + mt) * 16 + quad * 4 + r;
                W12p[packed_off(n, kcol)] = f2bf(acc[mt][r]);
            }
    } else if (bid < 192) {
        // ---- W1 -> bf16, packed. 4 consecutive k share a packed short4 slot.
        const int gid = (bid - 64) * 512 + tid;
        const int i4 = gid * 4;
        const int n = i4 >> 9, k = i4 & 511;
        const float4 a = *(const float4*)(W1 + i4);
        short4v sa = {f2bf(a.x), f2bf(a.y), f2bf(a.z), f2bf(a.w)};
        *(short4v*)(W1p + packed_off(n, k)) = sa;
    } else if (bid < 196) {
        // ---- b12 = W2@b1 + b2 : 4 blocks x 128 rows, 4 threads per row
        const int row = (bid - 192) * 128 + (tid >> 2);
        const int part = tid & 3;
        const float* wr = W2 + (size_t)row * 512;
        float acc = 0.0f;
#pragma unroll 4
        for (int i = 0; i < 32; ++i) {
            const float4 w = *(const float4*)(wr + (i * 4 + part) * 4);
            const float4 bb = *(const float4*)(b1 + (i * 4 + part) * 4);
            acc += w.x * bb.x + w.y * bb.y + w.z * bb.z + w.w * bb.w;
        }
        acc += __shfl_xor(acc, 1);
        acc += __shfl_xor(acc, 2);
        if (part == 0) b12[row] = acc + b2[row];
    } else if (bid == 196) {
        // ---- entries
        for (int t = tid; t <= B; t += 512) {
            if (t == B) {
                off[t] = T;
            } else {
                int lo = 0, hi = T;
                while (lo < hi) {
                    int mid = (lo + hi) >> 1;
                    if (db[mid] < t) lo = mid + 1; else hi = mid;
                }
                off[t] = lo;
            }
        }
        __syncthreads();
        for (int t = tid; t < B; t += 512)
            nch[t] = (off[t + 1] - off[t] + 63) >> 6;
        __syncthreads();
        if (tid == 0) {
            int s = 0;
            for (int i = 0; i < B; ++i) { scan[i] = s; s += nch[i]; }
            scan[B] = s;
        }
        __syncthreads();
        for (int t = tid; t < B; t += 512) {
            int cnt = off[t + 1] - off[t];
            for (int j = 0; j < nch[t]; ++j) {
                int v = cnt - j * 64;
                if (v > 64) v = 64;
                entries[scan[t] + j] = make_int4(t, off[t] + j * 64, v, 0);
            }
        }
        int total = scan[B];
        for (int i = total + tid; i < maxent; i += 512)
            entries[i] = make_int4(0, 0, 0, 0);
    } else {
        // ---- zero num/den (2*B*512 floats = 131072)
        const int idx = (bid - 197) * 512 + tid;   // 0..16383
        float4 z = {0.0f, 0.0f, 0.0f, 0.0f};
        *(float4*)(numden + (size_t)idx * 8) = z;
        *(float4*)(numden + (size_t)idx * 8 + 4) = z;
    }
}

// ---------------------------------------------------------------------------
// Main fused kernel: one block = 64 nodes of one batch, 512 threads (8 waves),
// 2 blocks/CU (LDS exactly 64KB). Fresh blocks, grid=maxent.
// Schedule per block (M-split pipeline):
//   LN rows 0-31 (wave*4+r) -> issue rows 32-63 x-loads -> barrier ->
//   grp0 part1 (mt 0,1: rows 0-31; x-loads fly under 128 MFMAs) ->
//   LN finish rows 32-63 -> barrier -> grp0 part2 (mt 2,3) + epi ->
//   grp1 full sweep + epi.
// ---------------------------------------------------------------------------
__global__ __launch_bounds__(512, 4)
void esa_fused(const float* __restrict__ x, const float* __restrict__ gamma,
               const float* __restrict__ beta, const short* __restrict__ W1p,
               const short* __restrict__ W12p, const float* __restrict__ b1,
               const float* __restrict__ b12, const int4* __restrict__ entries,
               float* __restrict__ num, float* __restrict__ den) {
    __shared__ short ylds[64 * 512];   // 65,536 B exactly -> 2 blocks/CU
    const int4 e = entries[blockIdx.x];
    const int bat = e.x, start = e.y, valid = e.z;
    if (valid <= 0) return;

    const int tid = threadIdx.x;
    const int wave = tid >> 6;          // 0..7
    const int lane = tid & 63;
    const int quad = lane >> 4;
    const int l16 = lane & 15;

    const float4 g0 = *(const float4*)(gamma + lane * 8);
    const float4 g1 = *(const float4*)(gamma + lane * 8 + 4);
    const float4 be0 = *(const float4*)(beta + lane * 8);
    const float4 be1 = *(const float4*)(beta + lane * 8 + 4);

    // LN math + swizzled LDS store for 4 rows at block-row mbase + wave*4 + r
    auto lnstore = [&](const float4* A, const float4* Bv, int mbase) {
        float s[4], ss[4];
#pragma unroll
        for (int r = 0; r < 4; ++r) {
            s[r] = A[r].x + A[r].y + A[r].z + A[r].w +
                   Bv[r].x + Bv[r].y + Bv[r].z + Bv[r].w;
            ss[r] = A[r].x * A[r].x + A[r].y * A[r].y + A[r].z * A[r].z +
                    A[r].w * A[r].w + Bv[r].x * Bv[r].x + Bv[r].y * Bv[r].y +
                    Bv[r].z * Bv[r].z + Bv[r].w * Bv[r].w;
        }
#pragma unroll
        for (int o = 1; o <= 32; o <<= 1) {     // 4 interleaved chains
#pragma unroll
            for (int r = 0; r < 4; ++r) {
                s[r] += __shfl_xor(s[r], o);
                ss[r] += __shfl_xor(ss[r], o);
            }
        }
#pragma unroll
        for (int r = 0; r < 4; ++r) {
            const int m = mbase + wave * 4 + r;
            const float mu = s[r] * (1.0f / 512.0f);
            const float var = ss[r] * (1.0f / 512.0f) - mu * mu;
            const float rstd = rsqrtf(var + 1e-5f);
            short8 outv;
            outv[0] = f2bf((A[r].x - mu) * rstd * g0.x + be0.x);
            outv[1] = f2bf((A[r].y - mu) * rstd * g0.y + be0.y);
            outv[2] = f2bf((A[r].z - mu) * rstd * g0.z + be0.z);
            outv[3] = f2bf((A[r].w - mu) * rstd * g0.w + be0.w);
            outv[4] = f2bf((Bv[r].x - mu) * rstd * g1.x + be1.x);
            outv[5] = f2bf((Bv[r].y - mu) * rstd * g1.y + be1.y);
            outv[6] = f2bf((Bv[r].z - mu) * rstd * g1.z + be1.z);
            outv[7] = f2bf((Bv[r].w - mu) * rstd * g1.w + be1.w);
            // XOR swizzle: column-block lane stored at lane ^ (m&7)
            *(short8*)&ylds[m * 512 + ((lane ^ (m & 7)) * 8)] = outv;
        }
    };

    // ---- Phase 1a: LN rows 0..31 (this wave: rows wave*4..+3)
    float4 ra[4], rb[4], ra1[4], rb1[4];
#pragma unroll
    for (int r = 0; r < 4; ++r) {
        const int m = wave * 4 + r;
        const int mc = m < valid ? m : valid - 1;       // clamp: in-batch
        const float* p = x + (size_t)(start + mc) * 512 + lane * 8;
        ra[r] = *(const float4*)p;
        rb[r] = *(const float4*)(p + 4);
    }
    lnstore(ra, rb, 0);

    // ---- Phase 1b-issue: x-loads for rows 32..63; consumed after part1
#pragma unroll
    for (int r = 0; r < 4; ++r) {
        const int m = 32 + wave * 4 + r;
        const int mc = m < valid ? m : valid - 1;
        const float* p = x + (size_t)(start + mc) * 512 + lane * 8;
        ra1[r] = *(const float4*)p;
        rb1[r] = *(const float4*)(p + 4);
    }
    __syncthreads();    // y rows 0..31 complete

    const int xr7 = l16 & 7;
    const short* abase = ylds + l16 * 512;
    const bool full = (valid >= 64);

    // Epilogue: C/D layout col=lane&15, row=quad*4+reg (m89-verified)
    auto epi = [&](const f32x4 (&ac)[2][4], const f32x4 (&af)[2][4], int n0) {
#pragma unroll
        for (int nt = 0; nt < 2; ++nt) {
            const int n = n0 + nt * 16 + l16;
            const float bb1 = b1[n];
            const float bb2 = b12[n];
            float se = 0.0f, sec = 0.0f;
            if (full) {
                // wave-uniform fast path: every row valid, no compares
#pragma unroll
                for (int mt = 0; mt < 4; ++mt) {
#pragma unroll
                    for (int r2 = 0; r2 < 4; ++r2) {
                        const float cap = ac[nt][mt][r2] + bb1;
                        const float ev = __expf(af[nt][mt][r2] + bb2);
                        se += ev;
                        sec += ev * cap;
                    }
                }
            } else {
#pragma unroll
                for (int mt = 0; mt < 4; ++mt) {
#pragma unroll
                    for (int r2 = 0; r2 < 4; ++r2) {
                        const int m = mt * 16 + quad * 4 + r2;
                        if (m < valid) {
                            const float cap = ac[nt][mt][r2] + bb1;
                            const float ev = __expf(af[nt][mt][r2] + bb2);
                            se += ev;
                            sec += ev * cap;
                        }
                    }
                }
            }
            se += __shfl_xor(se, 16);
            se += __shfl_xor(se, 32);
            sec += __shfl_xor(sec, 16);
            sec += __shfl_xor(sec, 32);
            if (quad == 0) atomicAdd(&den[(size_t)bat * 512 + n], se);
            else if (quad == 1) atomicAdd(&num[(size_t)bat * 512 + n], sec);
        }
    };

    // ---- grp0: cols wave*64 .. +31, M-split into two K-sweeps
    {
        const int ntile0 = wave * 4;
        const short* w1t0 = W1p + (size_t)ntile0 * 8192 + lane * 8;
        const short* w1t1 = w1t0 + 8192;
        const short* w2t0 = W12p + (size_t)ntile0 * 8192 + lane * 8;
        const short* w2t1 = w2t0 + 8192;

        f32x4 acc_c[2][4], acc_f[2][4];
#pragma unroll
        for (int nt = 0; nt < 2; ++nt)
#pragma unroll
            for (int mt = 0; mt < 4; ++mt) {
                acc_c[nt][mt] = (f32x4)0.0f;
                acc_f[nt][mt] = (f32x4)0.0f;
            }

        // part1: mt 0,1 (rows 0..31) — rows 32-63 x-loads fly under these MFMAs
#pragma unroll 2
        for (int k0 = 0; k0 < 16; ++k0) {
            const int blk = ((k0 << 2) | quad) ^ xr7;   // swizzled A block
            const short* ap = abase + blk * 8;
            const short8 af0 = *(const short8*)(ap);
            const short8 af1 = *(const short8*)(ap + 16 * 512);
            const short8 b10 = *(const short8*)(w1t0 + k0 * 512);
            const short8 b11 = *(const short8*)(w1t1 + k0 * 512);
            const short8 b20 = *(const short8*)(w2t0 + k0 * 512);
            const short8 b21 = *(const short8*)(w2t1 + k0 * 512);
            acc_c[0][0] = __builtin_amdgcn_mfma_f32_16x16x32_bf16(af0, b10, acc_c[0][0], 0, 0, 0);
            acc_c[0][1] = __builtin_amdgcn_mfma_f32_16x16x32_bf16(af1, b10, acc_c[0][1], 0, 0, 0);
            acc_c[1][0] = __builtin_amdgcn_mfma_f32_16x16x32_bf16(af0, b11, acc_c[1][0], 0, 0, 0);
            acc_c[1][1] = __builtin_amdgcn_mfma_f32_16x16x32_bf16(af1, b11, acc_c[1][1], 0, 0, 0);
            acc_f[0][0] = __builtin_amdgcn_mfma_f32_16x16x32_bf16(af0, b20, acc_f[0][0], 0, 0, 0);
            acc_f[0][1] = __builtin_amdgcn_mfma_f32_16x16x32_bf16(af1, b20, acc_f[0][1], 0, 0, 0);
            acc_f[1][0] = __builtin_amdgcn_mfma_f32_16x16x32_bf16(af0, b21, acc_f[1][0], 0, 0, 0);
            acc_f[1][1] = __builtin_amdgcn_mfma_f32_16x16x32_bf16(af1, b21, acc_f[1][1], 0, 0, 0);
        }

        // Phase 1b-finish: LN rows 32..63 (loads long in flight) + store.
        // Store region (rows 32-63) is disjoint from part1 reads (rows 0-31):
        // no barrier needed before the store, only after.
        lnstore(ra1, rb1, 32);
        __syncthreads();    // y rows 32..63 complete

        // part2: mt 2,3 (rows 32..63), second B sweep (L1/L2-warm)
#pragma unroll 2
        for (int k0 = 0; k0 < 16; ++k0) {
            const int blk = ((k0 << 2) | quad) ^ xr7;
            const short* ap = abase + blk * 8;
            const short8 af2 = *(const short8*)(ap + 32 * 512);
            const short8 af3 = *(const short8*)(ap + 48 * 512);
            const short8 b10 = *(const short8*)(w1t0 + k0 * 512);
            const short8 b11 = *(const short8*)(w1t1 + k0 * 512);
            const short8 b20 = *(const short8*)(w2t0 + k0 * 512);
            const short8 b21 = *(const short8*)(w2t1 + k0 * 512);
            acc_c[0][2] = __builtin_amdgcn_mfma_f32_16x16x32_bf16(af2, b10, acc_c[0][2], 0, 0, 0);
            acc_c[0][3] = __builtin_amdgcn_mfma_f32_16x16x32_bf16(af3, b10, acc_c[0][3], 0, 0, 0);
            acc_c[1][2] = __builtin_amdgcn_mfma_f32_16x16x32_bf16(af2, b11, acc_c[1][2], 0, 0, 0);
            acc_c[1][3] = __builtin_amdgcn_mfma_f32_16x16x32_bf16(af3, b11, acc_c[1][3], 0, 0, 0);
            acc_f[0][2] = __builtin_amdgcn_mfma_f32_16x16x32_bf16(af2, b20, acc_f[0][2], 0, 0, 0);
            acc_f[0][3] = __builtin_amdgcn_mfma_f32_16x16x32_bf16(af3, b20, acc_f[0][3], 0, 0, 0);
            acc_f[1][2] = __builtin_amdgcn_mfma_f32_16x16x32_bf16(af2, b21, acc_f[1][2], 0, 0, 0);
            acc_f[1][3] = __builtin_amdgcn_mfma_f32_16x16x32_bf16(af3, b21, acc_f[1][3], 0, 0, 0);
        }
        epi(acc_c, acc_f, wave * 64);
    }

    // ---- grp1: cols wave*64+32 .. +63, single full sweep (y complete)
    {
        const int ntile0 = wave * 4 + 2;
        const short* w1t0 = W1p + (size_t)ntile0 * 8192 + lane * 8;
        const short* w1t1 = w1t0 + 8192;
        const short* w2t0 = W12p + (size_t)ntile0 * 8192 + lane * 8;
        const short* w2t1 = w2t0 + 8192;

        f32x4 acc_c[2][4], acc_f[2][4];
#pragma unroll
        for (int nt = 0; nt < 2; ++nt)
#pragma unroll
            for (int mt = 0; mt < 4; ++mt) {
                acc_c[nt][mt] = (f32x4)0.0f;
                acc_f[nt][mt] = (f32x4)0.0f;
            }
#pragma unroll 2
        for (int k0 = 0; k0 < 16; ++k0) {
            const int blk = ((k0 << 2) | quad) ^ xr7;
            const short* ap = abase + blk * 8;
            short8 afr[4];
#pragma unroll
            for (int mt = 0; mt < 4; ++mt)
                afr[mt] = *(const short8*)(ap + mt * 16 * 512);
            const short8 b10 = *(const short8*)(w1t0 + k0 * 512);
            const short8 b11 = *(const short8*)(w1t1 + k0 * 512);
            const short8 b20 = *(const short8*)(w2t0 + k0 * 512);
            const short8 b21 = *(const short8*)(w2t1 + k0 * 512);
#pragma unroll
            for (int mt = 0; mt < 4; ++mt) {
                acc_c[0][mt] = __builtin_amdgcn_mfma_f32_16x16x32_bf16(
                    afr[mt], b10, acc_c[0][mt], 0, 0, 0);
                acc_c[1][mt] = __builtin_amdgcn_mfma_f32_16x16x32_bf16(
                    afr[mt], b11, acc_c[1][mt], 0, 0, 0);
                acc_f[0][mt] = __builtin_amdgcn_mfma_f32_16x16x32_bf16(
                    afr[mt], b20, acc_f[0][mt], 0, 0, 0);
                acc_f[1][mt] = __builtin_amdgcn_mfma_f32_16x16x32_bf16(
                    afr[mt], b21, acc_f[1][mt], 0, 0, 0);
            }
        }
        epi(acc_c, acc_f, wave * 64 + 32);
    }
}

__global__ __launch_bounds__(256)
void esa_finalize(const float* __restrict__ num, const float* __restrict__ den,
                  float* __restrict__ out, int n) {
    const int i = blockIdx.x * 256 + threadIdx.x;
    if (i < n) {
        const float d = den[i];
        out[i] = d > 0.0f ? num[i] / d : 0.0f;
    }
}

extern "C" void kernel_launch(void* const* d_in, const int* in_sizes, int n_in,
                              void* d_out, int out_size, void* d_ws, size_t ws_size,
                              hipStream_t stream) {
    const float* x = (const float*)d_in[0];
    const int* db = (const int*)d_in[1];
    // d_in[2] = max_nodes (unused: chunking derived from actual counts)
    const float* gamma = (const float*)d_in[3];
    const float* beta = (const float*)d_in[4];
    const float* W1 = (const float*)d_in[5];
    const float* b1 = (const float*)d_in[6];
    const float* W2 = (const float*)d_in[7];
    const float* b2 = (const float*)d_in[8];
    float* out = (float*)d_out;

    const int C = in_sizes[3];        // 512
    const int D = in_sizes[6];        // 512
    const int T = in_sizes[0] / C;    // 131072
    const int B = out_size / D;       // 128
    const int maxent = B + (T + 63) / 64;   // 2176

    char* ws = (char*)d_ws;
    short* W1p = (short*)(ws);                      // 512 KB packed
    short* W12p = (short*)(ws + 524288);            // 512 KB packed
    float* b12 = (float*)(ws + 1048576);            // 2 KB
    int4* entries = (int4*)(ws + 1050624);          // maxent*16
    size_t numoff = (1050624 + (size_t)maxent * 16 + 255) & ~(size_t)255;
    float* num = (float*)(ws + numoff);             // B*D*4
    float* den = (float*)(ws + numoff + (size_t)B * D * 4);

    esa_prep_all<<<PREP_GRID, 512, 0, stream>>>(W1, W2, b1, b2, db, T, B,
                                                W1p, W12p, b12, entries, maxent,
                                                num);
    esa_fused<<<maxent, 512, 0, stream>>>(x, gamma, beta, W1p, W12p, b1, b12,
                                          entries, num, den);
    esa_finalize<<<(B * D + 255) / 256, 256, 0, stream>>>(num, den, out, B * D);
}